// Round 2
// baseline (1463.824 us; speedup 1.0000x reference)
//
#include <hip/hip_runtime.h>
#include <math.h>

#define G_   8
#define NPG_ 4096
#define HC_  16
#define LAT_ 64
#define FF_  512
#define EDIM_ 3
#define EH_  64
#define NN_  32768
#define EE_  393216

// ---------------- front-end ----------------
__global__ void k_front1(const float* __restrict__ x, const float* __restrict__ w,
                         const float* __restrict__ b, float* __restrict__ h1) {
  int c = blockIdx.x * blockDim.x + threadIdx.x;
  if (c >= FF_) return;
  float acc[G_];
#pragma unroll
  for (int g = 0; g < G_; g++) acc[g] = 0.f;
  for (int r = 0; r < LAT_; r++) {
    float wv = w[r * FF_ + c];
#pragma unroll
    for (int g = 0; g < G_; g++) acc[g] = fmaf(x[g * LAT_ + r], wv, acc[g]);
  }
#pragma unroll
  for (int g = 0; g < G_; g++) h1[g * FF_ + c] = acc[g] + b[c];
}

__global__ __launch_bounds__(512) void k_front2(const float* __restrict__ h1,
                                                const float* __restrict__ w,
                                                const float* __restrict__ b,
                                                float* __restrict__ hn) {
  __shared__ float sh[G_ * FF_];
  for (int i = threadIdx.x; i < G_ * FF_; i += blockDim.x) sh[i] = h1[i];
  __syncthreads();
  int g = threadIdx.x >> 6;
  int lane = threadIdx.x & 63;
  int c = blockIdx.x * 64 + lane;
  const float* shg = &sh[g * FF_];
  float acc = 0.f;
#pragma unroll 8
  for (int r = 0; r < FF_; r++) acc = fmaf(shg[r], w[r * (NPG_ * HC_) + c], acc);
  float v = acc + b[c];
  hn[g * (NPG_ * HC_) + c] = v > 0.f ? v : expm1f(v);
}

// ---------------- counting sort by src ----------------
__global__ void k_zero(int* __restrict__ p, int nv) {
  int i = blockIdx.x * blockDim.x + threadIdx.x;
  if (i < nv) p[i] = 0;
}
__global__ void k_hist(const int* __restrict__ src, int* __restrict__ cnt) {
  int e = blockIdx.x * blockDim.x + threadIdx.x;
  if (e < EE_) atomicAdd(&cnt[src[e]], 1);
}
__global__ __launch_bounds__(1024) void k_scan(const int* __restrict__ cnt,
                                               int* __restrict__ rowptr,
                                               int* __restrict__ cursor) {
  __shared__ int part[1024];
  int t = threadIdx.x;
  int base = t * 32;
  int loc[32];
  int s = 0;
#pragma unroll
  for (int i = 0; i < 32; i++) { loc[i] = s; s += cnt[base + i]; }
  part[t] = s;
  __syncthreads();
  for (int off = 1; off < 1024; off <<= 1) {
    int v = (t >= off) ? part[t - off] : 0;
    __syncthreads();
    part[t] += v;
    __syncthreads();
  }
  int pre = (t == 0) ? 0 : part[t - 1];
#pragma unroll
  for (int i = 0; i < 32; i++) {
    int v = pre + loc[i];
    rowptr[base + i] = v;
    cursor[base + i] = v;
  }
  if (t == 1023) rowptr[NN_] = part[1023];
}
__global__ void k_scatter(const int* __restrict__ src, int* __restrict__ cursor,
                          int* __restrict__ perm) {
  int e = blockIdx.x * blockDim.x + threadIdx.x;
  if (e < EE_) {
    int pos = atomicAdd(&cursor[src[e]], 1);
    perm[pos] = e;
  }
}

// ---------------- per-conv kernels ----------------
__global__ void k_nodeinit(const float* __restrict__ hn, const float* __restrict__ root,
                           const float* __restrict__ bias, float* __restrict__ out) {
  int idx = blockIdx.x * blockDim.x + threadIdx.x;
  if (idx >= NN_ * HC_) return;
  int nd = idx >> 4, o = idx & 15;
  float acc = bias[o];
#pragma unroll
  for (int i = 0; i < 16; i++) acc = fmaf(hn[nd * 16 + i], root[i * 16 + o], acc);
  out[idx] = acc;
}

// w2t[o*1024 + i*64 + h] = w2[h*256 + i*16 + o]
__global__ void k_w2t(const float* __restrict__ w2, float* __restrict__ w2t) {
  int idx = blockIdx.x * 256 + threadIdx.x;
  int o = idx >> 10, i = (idx >> 6) & 15, h = idx & 63;
  w2t[idx] = w2[h * 256 + i * 16 + o];
}

// Edge aggregation core for one node's edge range.
// Lane l: o=l&15, q=l>>4. M[j] = M[h=q*16+j][o].
// Each lane computes hidden for h=l; the 16 hidden values a lane needs are
// gathered with ds_bpermute from lanes q*16+j.
__device__ __forceinline__ void process_edges(
    int rs, int re, const float (&M)[16], float T,
    const int* __restrict__ perm, const int* __restrict__ dst,
    const float* __restrict__ ea, float w10, float w11, float w12, float b1l,
    int qaddr, int l, int o, float* __restrict__ hnext) {
  if (rs >= re) return;
  int e_n = perm[rs];
  int d_n = dst[e_n];
  float a0_n = ea[e_n * 3], a1_n = ea[e_n * 3 + 1], a2_n = ea[e_n * 3 + 2];
  for (int k = rs; k < re; k++) {
    int d = d_n;
    float a0 = a0_n, a1 = a1_n, a2 = a2_n;
    if (k + 1 < re) {
      int e2 = perm[k + 1];
      d_n = dst[e2];
      a0_n = ea[e2 * 3];
      a1_n = ea[e2 * 3 + 1];
      a2_n = ea[e2 * 3 + 2];
    }
    float hd = fmaf(a0, w10, fmaf(a1, w11, fmaf(a2, w12, b1l)));
    hd = fmaxf(hd, 0.f);
    float p = 0.f;
#pragma unroll
    for (int j = 0; j < 16; j++) {
      int hv = __builtin_amdgcn_ds_bpermute(qaddr + j * 4, __float_as_int(hd));
      p = fmaf(__int_as_float(hv), M[j], p);
    }
    p += __shfl_xor(p, 16);
    p += __shfl_xor(p, 32);
    if (l < 16) atomicAdd(&hnext[d * 16 + o], p + T);
  }
}

// One wave handles 2 consecutive source nodes (shares w2t reads).
__global__ __launch_bounds__(256) void k_edge(
    const float* __restrict__ hn, const int* __restrict__ perm,
    const int* __restrict__ rowptr, const int* __restrict__ dst,
    const float* __restrict__ ea, const float* __restrict__ w1,
    const float* __restrict__ b1, const float* __restrict__ w2t,
    const float* __restrict__ b2, float* __restrict__ hnext) {
  int tid = threadIdx.x;
  int wave = tid >> 6, l = tid & 63;
  int o = l & 15, q = l >> 4;
  int nA = (blockIdx.x * 4 + wave) * 2;
  int nB = nA + 1;

  int rsA = rowptr[nA];
  int reA = rowptr[nA + 1];  // == rsB
  int reB = rowptr[nB + 1];
  if (rsA >= reB) return;

  float MA[16], MB[16];
#pragma unroll
  for (int j = 0; j < 16; j++) { MA[j] = 0.f; MB[j] = 0.f; }
  float TA = 0.f, TB = 0.f;
  const float4* __restrict__ w2tv = (const float4*)w2t;
  int base4 = o * 256 + q * 4;
#pragma unroll
  for (int i = 0; i < 16; i++) {
    float xA = hn[nA * 16 + i];
    float xB = hn[nB * 16 + i];
    float bv = b2[i * 16 + o];
    TA = fmaf(xA, bv, TA);
    TB = fmaf(xB, bv, TB);
#pragma unroll
    for (int j4 = 0; j4 < 4; j4++) {
      float4 v = w2tv[base4 + i * 16 + j4];
      MA[j4 * 4 + 0] = fmaf(xA, v.x, MA[j4 * 4 + 0]);
      MA[j4 * 4 + 1] = fmaf(xA, v.y, MA[j4 * 4 + 1]);
      MA[j4 * 4 + 2] = fmaf(xA, v.z, MA[j4 * 4 + 2]);
      MA[j4 * 4 + 3] = fmaf(xA, v.w, MA[j4 * 4 + 3]);
      MB[j4 * 4 + 0] = fmaf(xB, v.x, MB[j4 * 4 + 0]);
      MB[j4 * 4 + 1] = fmaf(xB, v.y, MB[j4 * 4 + 1]);
      MB[j4 * 4 + 2] = fmaf(xB, v.z, MB[j4 * 4 + 2]);
      MB[j4 * 4 + 3] = fmaf(xB, v.w, MB[j4 * 4 + 3]);
    }
  }

  float w10 = w1[l], w11 = w1[64 + l], w12 = w1[128 + l], b1l = b1[l];
  int qaddr = (l & 48) << 2;  // = (q*16)*4

  process_edges(rsA, reA, MA, TA, perm, dst, ea, w10, w11, w12, b1l, qaddr, l, o, hnext);
  process_edges(reA, reB, MB, TB, perm, dst, ea, w10, w11, w12, b1l, qaddr, l, o, hnext);
}

__global__ void k_elu(const float* __restrict__ in, float* __restrict__ out) {
  int idx = blockIdx.x * blockDim.x + threadIdx.x;
  if (idx >= NN_ * HC_) return;
  float v = in[idx];
  out[idx] = v > 0.f ? v : expm1f(v);
}

// ---------------- launch ----------------
extern "C" void kernel_launch(void* const* d_in, const int* in_sizes, int n_in,
                              void* d_out, int out_size, void* d_ws, size_t ws_size,
                              hipStream_t stream) {
  const float* x    = (const float*)d_in[0];
  const int*   ei   = (const int*)d_in[1];
  const float* ea   = (const float*)d_in[2];
  const float* fc2w = (const float*)d_in[3];
  const float* fc2b = (const float*)d_in[4];
  const float* fc1w = (const float*)d_in[5];
  const float* fc1b = (const float*)d_in[6];
  float* out = (float*)d_out;

  float* ws    = (float*)d_ws;
  float* h1    = ws;                        // 4096
  float* hnode = ws + 4096;                 // N*16
  float* hnext = hnode + NN_ * HC_;         // N*16
  int* cnt     = (int*)(hnext + NN_ * HC_); // N
  int* rowptr  = cnt + NN_;                 // N+1
  int* cursor  = rowptr + NN_ + 1;          // N
  int* perm    = cursor + NN_;              // E
  float* w2t   = (float*)(perm + EE_);      // 16384

  const int* src = ei;
  const int* dstp = ei + EE_;

  k_front1<<<2, 256, 0, stream>>>(x, fc2w, fc2b, h1);
  k_front2<<<1024, 512, 0, stream>>>(h1, fc1w, fc1b, hnode);

  k_zero<<<(NN_ + 255) / 256, 256, 0, stream>>>(cnt, NN_);
  k_hist<<<(EE_ + 255) / 256, 256, 0, stream>>>(src, cnt);
  k_scan<<<1, 1024, 0, stream>>>(cnt, rowptr, cursor);
  k_scatter<<<(EE_ + 255) / 256, 256, 0, stream>>>(src, cursor, perm);

  for (int cv = 0; cv < 2; cv++) {
    const float* root = (const float*)d_in[7 + cv * 6];
    const float* cb   = (const float*)d_in[8 + cv * 6];
    const float* w1   = (const float*)d_in[9 + cv * 6];
    const float* b1   = (const float*)d_in[10 + cv * 6];
    const float* w2   = (const float*)d_in[11 + cv * 6];
    const float* b2   = (const float*)d_in[12 + cv * 6];
    k_w2t<<<64, 256, 0, stream>>>(w2, w2t);
    k_nodeinit<<<NN_ * HC_ / 256, 256, 0, stream>>>(hnode, root, cb, hnext);
    k_edge<<<NN_ / 8, 256, 0, stream>>>(hnode, perm, rowptr, dstp, ea, w1, b1,
                                        w2t, b2, hnext);
    k_elu<<<NN_ * HC_ / 256, 256, 0, stream>>>(hnext, cv == 0 ? hnode : out);
  }
}

// Round 3
// 801.845 us; speedup vs baseline: 1.8256x; 1.8256x over previous
//
#include <hip/hip_runtime.h>
#include <math.h>

#define G_   8
#define NPG_ 4096
#define HC_  16
#define LAT_ 64
#define FF_  512
#define EDIM_ 3
#define EH_  64
#define NN_  32768
#define EE_  393216

// ---------------- front-end ----------------
__global__ void k_front1(const float* __restrict__ x, const float* __restrict__ w,
                         const float* __restrict__ b, float* __restrict__ h1) {
  int c = blockIdx.x * blockDim.x + threadIdx.x;
  if (c >= FF_) return;
  float acc[G_];
#pragma unroll
  for (int g = 0; g < G_; g++) acc[g] = 0.f;
  for (int r = 0; r < LAT_; r++) {
    float wv = w[r * FF_ + c];
#pragma unroll
    for (int g = 0; g < G_; g++) acc[g] = fmaf(x[g * LAT_ + r], wv, acc[g]);
  }
#pragma unroll
  for (int g = 0; g < G_; g++) h1[g * FF_ + c] = acc[g] + b[c];
}

__global__ __launch_bounds__(512) void k_front2(const float* __restrict__ h1,
                                                const float* __restrict__ w,
                                                const float* __restrict__ b,
                                                float* __restrict__ hn) {
  __shared__ float sh[G_ * FF_];
  for (int i = threadIdx.x; i < G_ * FF_; i += blockDim.x) sh[i] = h1[i];
  __syncthreads();
  int g = threadIdx.x >> 6;
  int lane = threadIdx.x & 63;
  int c = blockIdx.x * 64 + lane;
  const float* shg = &sh[g * FF_];
  float acc = 0.f;
#pragma unroll 8
  for (int r = 0; r < FF_; r++) acc = fmaf(shg[r], w[r * (NPG_ * HC_) + c], acc);
  float v = acc + b[c];
  hn[g * (NPG_ * HC_) + c] = v > 0.f ? v : expm1f(v);
}

// ---------------- counting sort by src ----------------
__global__ void k_zero(int* __restrict__ p, int nv) {
  int i = blockIdx.x * blockDim.x + threadIdx.x;
  if (i < nv) p[i] = 0;
}
__global__ void k_hist(const int* __restrict__ src, int* __restrict__ cnt) {
  int e = blockIdx.x * blockDim.x + threadIdx.x;
  if (e < EE_) atomicAdd(&cnt[src[e]], 1);
}
__global__ __launch_bounds__(1024) void k_scan(const int* __restrict__ cnt,
                                               int* __restrict__ rowptr,
                                               int* __restrict__ cursor) {
  __shared__ int part[1024];
  int t = threadIdx.x;
  int base = t * 32;
  int loc[32];
  int s = 0;
#pragma unroll
  for (int i = 0; i < 32; i++) { loc[i] = s; s += cnt[base + i]; }
  part[t] = s;
  __syncthreads();
  for (int off = 1; off < 1024; off <<= 1) {
    int v = (t >= off) ? part[t - off] : 0;
    __syncthreads();
    part[t] += v;
    __syncthreads();
  }
  int pre = (t == 0) ? 0 : part[t - 1];
#pragma unroll
  for (int i = 0; i < 32; i++) {
    int v = pre + loc[i];
    rowptr[base + i] = v;
    cursor[base + i] = v;
  }
  if (t == 1023) rowptr[NN_] = part[1023];
}
__global__ void k_scatter(const int* __restrict__ src, int* __restrict__ cursor,
                          int* __restrict__ perm) {
  int e = blockIdx.x * blockDim.x + threadIdx.x;
  if (e < EE_) {
    int pos = atomicAdd(&cursor[src[e]], 1);
    perm[pos] = e;
  }
}

// ---------------- per-conv kernels ----------------
__global__ void k_nodeinit(const float* __restrict__ hn, const float* __restrict__ root,
                           const float* __restrict__ bias, float* __restrict__ out) {
  int idx = blockIdx.x * blockDim.x + threadIdx.x;
  if (idx >= NN_ * HC_) return;
  int nd = idx >> 4, o = idx & 15;
  float acc = bias[o];
#pragma unroll
  for (int i = 0; i < 16; i++) acc = fmaf(hn[nd * 16 + i], root[i * 16 + o], acc);
  out[idx] = acc;
}

// w2t[o*1024 + i*64 + h] = w2[h*256 + i*16 + o]
__global__ void k_w2t(const float* __restrict__ w2, float* __restrict__ w2t) {
  int idx = blockIdx.x * 256 + threadIdx.x;
  int o = idx >> 10, i = (idx >> 6) & 15, h = idx & 63;
  w2t[idx] = w2[h * 256 + i * 16 + o];
}

// Edge aggregation. One wave per source node (4 waves/block), no LDS.
// Lane l: o = l&15, q = l>>4. Lane holds M[h=q*16+j][o], j=0..15:
//   M[h][o] = sum_i x_n[i] * w2[h][i*16+o]   (read from w2t, coalesced f4)
// Per edge: each o-group redundantly computes its 16 hidden values in regs,
// dot with M, 2-step shfl reduce over q, 16-lane atomicAdd.
__global__ __launch_bounds__(256, 4) void k_edge(
    const float* __restrict__ hn, const int* __restrict__ perm,
    const int* __restrict__ rowptr, const int* __restrict__ dst,
    const float* __restrict__ ea, const float* __restrict__ w1,
    const float* __restrict__ b1, const float* __restrict__ w2t,
    const float* __restrict__ b2, float* __restrict__ hnext) {
  int tid = threadIdx.x;
  int wave = tid >> 6, l = tid & 63;
  int o = l & 15, q = l >> 4;
  int n = blockIdx.x * 4 + wave;

  int rs = rowptr[n], re = rowptr[n + 1];
  if (rs >= re) return;

  float xv[16];
#pragma unroll
  for (int i = 0; i < 16; i++) xv[i] = hn[n * 16 + i];

  float M[16];
#pragma unroll
  for (int j = 0; j < 16; j++) M[j] = 0.f;
  float T = 0.f;
  const float4* __restrict__ w2tv = (const float4*)w2t;
  int base4 = o * 256 + q * 4;
#pragma unroll
  for (int i = 0; i < 16; i++) {
    float xi = xv[i];
    T = fmaf(xi, b2[i * 16 + o], T);
#pragma unroll
    for (int j4 = 0; j4 < 4; j4++) {
      float4 v = w2tv[base4 + i * 16 + j4];
      M[j4 * 4 + 0] = fmaf(xi, v.x, M[j4 * 4 + 0]);
      M[j4 * 4 + 1] = fmaf(xi, v.y, M[j4 * 4 + 1]);
      M[j4 * 4 + 2] = fmaf(xi, v.z, M[j4 * 4 + 2]);
      M[j4 * 4 + 3] = fmaf(xi, v.w, M[j4 * 4 + 3]);
    }
  }

  // per-lane edge-MLP weights for h = q*16 + j (loaded after M-setup to keep
  // peak VGPR pressure down)
  float w1r0[16], w1r1[16], w1r2[16], b1r[16];
#pragma unroll
  for (int j = 0; j < 16; j++) {
    int h = q * 16 + j;
    w1r0[j] = w1[h];
    w1r1[j] = w1[64 + h];
    w1r2[j] = w1[128 + h];
    b1r[j] = b1[h];
  }

  // software-pipelined edge loop
  int e_n = perm[rs];
  int d_n = dst[e_n];
  float a0_n = ea[e_n * 3], a1_n = ea[e_n * 3 + 1], a2_n = ea[e_n * 3 + 2];
  for (int k = rs; k < re; k++) {
    int d = d_n;
    float a0 = a0_n, a1 = a1_n, a2 = a2_n;
    if (k + 1 < re) {
      int e2 = perm[k + 1];
      d_n = dst[e2];
      a0_n = ea[e2 * 3];
      a1_n = ea[e2 * 3 + 1];
      a2_n = ea[e2 * 3 + 2];
    }
    float p = 0.f;
#pragma unroll
    for (int j = 0; j < 16; j++) {
      float hd = fmaf(a0, w1r0[j], fmaf(a1, w1r1[j], fmaf(a2, w1r2[j], b1r[j])));
      hd = fmaxf(hd, 0.f);
      p = fmaf(hd, M[j], p);
    }
    p += __shfl_xor(p, 16);
    p += __shfl_xor(p, 32);
    if (l < 16) atomicAdd(&hnext[d * 16 + o], p + T);
  }
}

__global__ void k_elu(const float* __restrict__ in, float* __restrict__ out) {
  int idx = blockIdx.x * blockDim.x + threadIdx.x;
  if (idx >= NN_ * HC_) return;
  float v = in[idx];
  out[idx] = v > 0.f ? v : expm1f(v);
}

// ---------------- launch ----------------
extern "C" void kernel_launch(void* const* d_in, const int* in_sizes, int n_in,
                              void* d_out, int out_size, void* d_ws, size_t ws_size,
                              hipStream_t stream) {
  const float* x    = (const float*)d_in[0];
  const int*   ei   = (const int*)d_in[1];
  const float* ea   = (const float*)d_in[2];
  const float* fc2w = (const float*)d_in[3];
  const float* fc2b = (const float*)d_in[4];
  const float* fc1w = (const float*)d_in[5];
  const float* fc1b = (const float*)d_in[6];
  float* out = (float*)d_out;

  float* ws    = (float*)d_ws;
  float* h1    = ws;                        // 4096
  float* hnode = ws + 4096;                 // N*16
  float* hnext = hnode + NN_ * HC_;         // N*16
  int* cnt     = (int*)(hnext + NN_ * HC_); // N
  int* rowptr  = cnt + NN_;                 // N+1
  int* cursor  = rowptr + NN_ + 1;          // N
  int* perm    = cursor + NN_;              // E
  float* w2t   = (float*)(perm + EE_);      // 16384

  const int* src = ei;
  const int* dstp = ei + EE_;

  k_front1<<<2, 256, 0, stream>>>(x, fc2w, fc2b, h1);
  k_front2<<<1024, 512, 0, stream>>>(h1, fc1w, fc1b, hnode);

  k_zero<<<(NN_ + 255) / 256, 256, 0, stream>>>(cnt, NN_);
  k_hist<<<(EE_ + 255) / 256, 256, 0, stream>>>(src, cnt);
  k_scan<<<1, 1024, 0, stream>>>(cnt, rowptr, cursor);
  k_scatter<<<(EE_ + 255) / 256, 256, 0, stream>>>(src, cursor, perm);

  for (int cv = 0; cv < 2; cv++) {
    const float* root = (const float*)d_in[7 + cv * 6];
    const float* cb   = (const float*)d_in[8 + cv * 6];
    const float* w1   = (const float*)d_in[9 + cv * 6];
    const float* b1   = (const float*)d_in[10 + cv * 6];
    const float* w2   = (const float*)d_in[11 + cv * 6];
    const float* b2   = (const float*)d_in[12 + cv * 6];
    k_w2t<<<64, 256, 0, stream>>>(w2, w2t);
    k_nodeinit<<<NN_ * HC_ / 256, 256, 0, stream>>>(hnode, root, cb, hnext);
    k_edge<<<NN_ / 4, 256, 0, stream>>>(hnode, perm, rowptr, dstp, ea, w1, b1,
                                        w2t, b2, hnext);
    k_elu<<<NN_ * HC_ / 256, 256, 0, stream>>>(hnext, cv == 0 ? hnode : out);
  }
}

// Round 4
// 697.553 us; speedup vs baseline: 2.0985x; 1.1495x over previous
//
#include <hip/hip_runtime.h>
#include <math.h>

#define G_   8
#define NPG_ 4096
#define HC_  16
#define LAT_ 64
#define FF_  512
#define EDIM_ 3
#define EH_  64
#define NN_  32768
#define EE_  393216

// ---------------- front-end ----------------
__global__ void k_front1(const float* __restrict__ x, const float* __restrict__ w,
                         const float* __restrict__ b, float* __restrict__ h1) {
  int c = blockIdx.x * blockDim.x + threadIdx.x;
  if (c >= FF_) return;
  float acc[G_];
#pragma unroll
  for (int g = 0; g < G_; g++) acc[g] = 0.f;
  for (int r = 0; r < LAT_; r++) {
    float wv = w[r * FF_ + c];
#pragma unroll
    for (int g = 0; g < G_; g++) acc[g] = fmaf(x[g * LAT_ + r], wv, acc[g]);
  }
#pragma unroll
  for (int g = 0; g < G_; g++) h1[g * FF_ + c] = acc[g] + b[c];
}

__global__ __launch_bounds__(512) void k_front2(const float* __restrict__ h1,
                                                const float* __restrict__ w,
                                                const float* __restrict__ b,
                                                float* __restrict__ hn) {
  __shared__ float sh[G_ * FF_];
  for (int i = threadIdx.x; i < G_ * FF_; i += blockDim.x) sh[i] = h1[i];
  __syncthreads();
  int g = threadIdx.x >> 6;
  int lane = threadIdx.x & 63;
  int c = blockIdx.x * 64 + lane;
  const float* shg = &sh[g * FF_];
  float acc = 0.f;
#pragma unroll 8
  for (int r = 0; r < FF_; r++) acc = fmaf(shg[r], w[r * (NPG_ * HC_) + c], acc);
  float v = acc + b[c];
  hn[g * (NPG_ * HC_) + c] = v > 0.f ? v : expm1f(v);
}

// ---------------- counting sort by src ----------------
__global__ void k_zero(int* __restrict__ p, int nv) {
  int i = blockIdx.x * blockDim.x + threadIdx.x;
  if (i < nv) p[i] = 0;
}
__global__ void k_hist(const int* __restrict__ src, int* __restrict__ cnt) {
  int e = blockIdx.x * blockDim.x + threadIdx.x;
  if (e < EE_) atomicAdd(&cnt[src[e]], 1);
}
__global__ __launch_bounds__(1024) void k_scan(const int* __restrict__ cnt,
                                               int* __restrict__ rowptr,
                                               int* __restrict__ cursor) {
  __shared__ int part[1024];
  int t = threadIdx.x;
  int base = t * 32;
  int loc[32];
  int s = 0;
#pragma unroll
  for (int i = 0; i < 32; i++) { loc[i] = s; s += cnt[base + i]; }
  part[t] = s;
  __syncthreads();
  for (int off = 1; off < 1024; off <<= 1) {
    int v = (t >= off) ? part[t - off] : 0;
    __syncthreads();
    part[t] += v;
    __syncthreads();
  }
  int pre = (t == 0) ? 0 : part[t - 1];
#pragma unroll
  for (int i = 0; i < 32; i++) {
    int v = pre + loc[i];
    rowptr[base + i] = v;
    cursor[base + i] = v;
  }
  if (t == 1023) rowptr[NN_] = part[1023];
}
__global__ void k_scatter(const int* __restrict__ src, int* __restrict__ cursor,
                          int* __restrict__ perm) {
  int e = blockIdx.x * blockDim.x + threadIdx.x;
  if (e < EE_) {
    int pos = atomicAdd(&cursor[src[e]], 1);
    perm[pos] = e;
  }
}

// Gather edge data into src-sorted order (run ONCE, reused by both convs):
// eas4[k] = (ea0, ea1, ea2, bits(dst)) of edge perm[k]; zero padding past E.
__global__ void k_gather(const int* __restrict__ perm, const int* __restrict__ dst,
                         const float* __restrict__ ea, float4* __restrict__ eas4) {
  int e = blockIdx.x * blockDim.x + threadIdx.x;
  if (e >= EE_ + 8) return;
  float4 v = make_float4(0.f, 0.f, 0.f, __int_as_float(0));
  if (e < EE_) {
    int eid = perm[e];
    v.x = ea[eid * 3];
    v.y = ea[eid * 3 + 1];
    v.z = ea[eid * 3 + 2];
    v.w = __int_as_float(dst[eid]);
  }
  eas4[e] = v;
}

// ---------------- per-conv kernels ----------------
__global__ void k_nodeinit(const float* __restrict__ hn, const float* __restrict__ root,
                           const float* __restrict__ bias, float* __restrict__ out) {
  int idx = blockIdx.x * blockDim.x + threadIdx.x;
  if (idx >= NN_ * HC_) return;
  int nd = idx >> 4, o = idx & 15;
  float acc = bias[o];
#pragma unroll
  for (int i = 0; i < 16; i++) acc = fmaf(hn[nd * 16 + i], root[i * 16 + o], acc);
  out[idx] = acc;
}

// w2t[o*1024 + i*64 + h] = w2[h*256 + i*16 + o];  w1p4[h] = (w1[0..2][h], b1[h])
__global__ void k_wprep(const float* __restrict__ w2, const float* __restrict__ w1,
                        const float* __restrict__ b1, float* __restrict__ w2t,
                        float4* __restrict__ w1p4) {
  int idx = blockIdx.x * 256 + threadIdx.x;
  if (idx < 16384) {
    int o = idx >> 10, i = (idx >> 6) & 15, h = idx & 63;
    w2t[idx] = w2[h * 256 + i * 16 + o];
  }
  if (idx < 64) {
    w1p4[idx] = make_float4(w1[idx], w1[64 + idx], w1[128 + idx], b1[idx]);
  }
}

// Edge aggregation. One wave per source node (4 waves/block), no LDS.
// Lane l: o=l&15, q=l>>4. Lane holds M[h=q*16+j][o] for j=0..15.
// Edge loop: 4 edges per iteration, double-buffered sequential float4 loads
// (ea pre-gathered into sorted order), w1 re-read from L1 per j (shared by
// the 4 batched edges) to keep VGPR pressure low.
__global__ __launch_bounds__(256, 4) void k_edge(
    const float* __restrict__ hn, const int* __restrict__ rowptr,
    const float4* __restrict__ eas4, const float4* __restrict__ w1p4,
    const float* __restrict__ w2t, const float* __restrict__ b2,
    float* __restrict__ hnext) {
  int tid = threadIdx.x;
  int wave = tid >> 6, l = tid & 63;
  int o = l & 15, q = l >> 4;
  int n = blockIdx.x * 4 + wave;

  int rs = rowptr[n], re = rowptr[n + 1];
  if (rs >= re) return;

  float xv[16];
#pragma unroll
  for (int i = 0; i < 16; i++) xv[i] = hn[n * 16 + i];

  float M[16];
#pragma unroll
  for (int j = 0; j < 16; j++) M[j] = 0.f;
  float T = 0.f;
  const float4* __restrict__ w2tv = (const float4*)w2t;
  int base4 = o * 256 + q * 4;
#pragma unroll
  for (int i = 0; i < 16; i++) {
    float xi = xv[i];
    T = fmaf(xi, b2[i * 16 + o], T);
#pragma unroll
    for (int j4 = 0; j4 < 4; j4++) {
      float4 v = w2tv[base4 + i * 16 + j4];
      M[j4 * 4 + 0] = fmaf(xi, v.x, M[j4 * 4 + 0]);
      M[j4 * 4 + 1] = fmaf(xi, v.y, M[j4 * 4 + 1]);
      M[j4 * 4 + 2] = fmaf(xi, v.z, M[j4 * 4 + 2]);
      M[j4 * 4 + 3] = fmaf(xi, v.w, M[j4 * 4 + 3]);
    }
  }

  const float4* __restrict__ w1v = &w1p4[q * 16];

  float4 c0 = eas4[rs], c1 = eas4[rs + 1], c2 = eas4[rs + 2], c3 = eas4[rs + 3];
  for (int k = rs; k < re; k += 4) {
    // prefetch next chunk (padding guarantees in-bounds reads)
    float4 n0 = eas4[k + 4], n1 = eas4[k + 5], n2 = eas4[k + 6], n3 = eas4[k + 7];

    float p0 = 0.f, p1 = 0.f, p2 = 0.f, p3 = 0.f;
#pragma unroll
    for (int j = 0; j < 16; j++) {
      float4 wv = w1v[j];
      float m = M[j];
      float h0 = fmaxf(fmaf(c0.z, wv.z, fmaf(c0.y, wv.y, fmaf(c0.x, wv.x, wv.w))), 0.f);
      float h1 = fmaxf(fmaf(c1.z, wv.z, fmaf(c1.y, wv.y, fmaf(c1.x, wv.x, wv.w))), 0.f);
      float h2 = fmaxf(fmaf(c2.z, wv.z, fmaf(c2.y, wv.y, fmaf(c2.x, wv.x, wv.w))), 0.f);
      float h3 = fmaxf(fmaf(c3.z, wv.z, fmaf(c3.y, wv.y, fmaf(c3.x, wv.x, wv.w))), 0.f);
      p0 = fmaf(h0, m, p0);
      p1 = fmaf(h1, m, p1);
      p2 = fmaf(h2, m, p2);
      p3 = fmaf(h3, m, p3);
    }
    p0 += __shfl_xor(p0, 16); p1 += __shfl_xor(p1, 16);
    p2 += __shfl_xor(p2, 16); p3 += __shfl_xor(p3, 16);
    p0 += __shfl_xor(p0, 32); p1 += __shfl_xor(p1, 32);
    p2 += __shfl_xor(p2, 32); p3 += __shfl_xor(p3, 32);

    if (l < 16) {
      atomicAdd(&hnext[__float_as_int(c0.w) * 16 + o], p0 + T);
      if (k + 1 < re) atomicAdd(&hnext[__float_as_int(c1.w) * 16 + o], p1 + T);
      if (k + 2 < re) atomicAdd(&hnext[__float_as_int(c2.w) * 16 + o], p2 + T);
      if (k + 3 < re) atomicAdd(&hnext[__float_as_int(c3.w) * 16 + o], p3 + T);
    }
    c0 = n0; c1 = n1; c2 = n2; c3 = n3;
  }
}

__global__ void k_elu(const float* __restrict__ in, float* __restrict__ out) {
  int idx = blockIdx.x * blockDim.x + threadIdx.x;
  if (idx >= NN_ * HC_) return;
  float v = in[idx];
  out[idx] = v > 0.f ? v : expm1f(v);
}

// ---------------- launch ----------------
extern "C" void kernel_launch(void* const* d_in, const int* in_sizes, int n_in,
                              void* d_out, int out_size, void* d_ws, size_t ws_size,
                              hipStream_t stream) {
  const float* x    = (const float*)d_in[0];
  const int*   ei   = (const int*)d_in[1];
  const float* ea   = (const float*)d_in[2];
  const float* fc2w = (const float*)d_in[3];
  const float* fc2b = (const float*)d_in[4];
  const float* fc1w = (const float*)d_in[5];
  const float* fc1b = (const float*)d_in[6];
  float* out = (float*)d_out;

  float* ws = (float*)d_ws;
  // float-offset layout (16B alignment kept for float4 arrays)
  float*  h1     = ws;                         // @0        4096
  float*  hnode  = ws + 4096;                  // @4096     524288
  float*  hnext  = ws + 528384;                // @528384   524288
  float*  w2t    = ws + 1052672;               // @1052672  16384
  float4* w1p4   = (float4*)(ws + 1069056);    // @1069056  256 floats
  float4* eas4   = (float4*)(ws + 1069312);    // @1069312  (E+8)*4 floats
  int*    cnt    = (int*)(ws + 1069312 + (EE_ + 8) * 4);  // N
  int*    rowptr = cnt + NN_;                  // N+1
  int*    cursor = rowptr + NN_ + 1;           // N
  int*    perm   = cursor + NN_;               // E

  const int* src  = ei;
  const int* dstp = ei + EE_;

  k_front1<<<2, 256, 0, stream>>>(x, fc2w, fc2b, h1);
  k_front2<<<1024, 512, 0, stream>>>(h1, fc1w, fc1b, hnode);

  k_zero<<<(NN_ + 255) / 256, 256, 0, stream>>>(cnt, NN_);
  k_hist<<<(EE_ + 255) / 256, 256, 0, stream>>>(src, cnt);
  k_scan<<<1, 1024, 0, stream>>>(cnt, rowptr, cursor);
  k_scatter<<<(EE_ + 255) / 256, 256, 0, stream>>>(src, cursor, perm);
  k_gather<<<(EE_ + 8 + 255) / 256, 256, 0, stream>>>(perm, dstp, ea, eas4);

  for (int cv = 0; cv < 2; cv++) {
    const float* root = (const float*)d_in[7 + cv * 6];
    const float* cb   = (const float*)d_in[8 + cv * 6];
    const float* w1   = (const float*)d_in[9 + cv * 6];
    const float* b1   = (const float*)d_in[10 + cv * 6];
    const float* w2   = (const float*)d_in[11 + cv * 6];
    const float* b2   = (const float*)d_in[12 + cv * 6];
    k_wprep<<<64, 256, 0, stream>>>(w2, w1, b1, w2t, w1p4);
    k_nodeinit<<<NN_ * HC_ / 256, 256, 0, stream>>>(hnode, root, cb, hnext);
    k_edge<<<NN_ / 4, 256, 0, stream>>>(hnode, rowptr, eas4, w1p4, w2t, b2, hnext);
    k_elu<<<NN_ * HC_ / 256, 256, 0, stream>>>(hnext, cv == 0 ? hnode : out);
  }
}